// Round 6
// baseline (47.791 us; speedup 1.0000x reference)
//
#include <hip/hip_runtime.h>
#include <math.h>

// VectorQuantizer: B=4, T=2048, DIM=64, NUM_CODES=512
// out = [ k as float (8192) | z_q (8192*64) ]
//
// R5: lane = query (query vector in 64 VGPRs), codes split 32 ways
// (16 codes per lane), code rows read as WAVE-UNIFORM global float4 loads
// (1 segment per instr, L1-resident table) -- no LDS, no gathers.
// 4096 waves = 4 waves/SIMD. Distance math bit-matches the validated path:
// acc[d&7] ascending-dim accumulation, fixed combine tree, IEEE sqrtf,
// strict-< ascending-index argmin, lexicographic cross-chunk reduce.

#define NQ      8192
#define VDIM    64
#define NCODES  512
#define NCHUNK  32
#define CPC     (NCODES / NCHUNK)     // 16 codes per chunk

__global__ __launch_bounds__(256, 4) void vq_dist_kernel(
    const float* __restrict__ inp,     // [NQ][VDIM]
    const float* __restrict__ table,   // [NCODES][VDIM]
    float* __restrict__ wnorm,         // [NCHUNK][NQ]
    int* __restrict__ widx)            // [NCHUNK][NQ]
{
    const int lane  = threadIdx.x & 63;
    const int wave  = threadIdx.x >> 6;
    const int chunk = blockIdx.x & (NCHUNK - 1);     // code chunk (fast dim)
    const int qg    = (blockIdx.x >> 5) * 4 + wave;  // query group 0..127
    const int q     = qg * 64 + lane;

    // ---- Query vector into registers (16 x float4 per lane) ----
    float qv[VDIM];
    {
        const float4* qp = reinterpret_cast<const float4*>(inp + (size_t)q * VDIM);
#pragma unroll
        for (int i = 0; i < 16; ++i) {
            float4 v = qp[i];
            qv[4*i+0] = v.x; qv[4*i+1] = v.y; qv[4*i+2] = v.z; qv[4*i+3] = v.w;
        }
    }

    float best = INFINITY;
    int   bidx = 0;

#pragma clang loop unroll(disable)
    for (int c = 0; c < CPC; ++c) {
        const int code = chunk * CPC + c;
        const float4* crow = reinterpret_cast<const float4*>(table + (size_t)code * VDIM);

        float acc[8];
#pragma unroll
        for (int m = 0; m < 8; ++m) acc[m] = 0.0f;

        // 4 batches of 4 float4s (16 dims each); batch b covers dims 16b..16b+15,
        // so elem e -> acc[e&7], updates in ascending dim order (bit-exact).
#pragma unroll
        for (int b = 0; b < 4; ++b) {
            float4 cv0 = crow[b * 4 + 0];
            float4 cv1 = crow[b * 4 + 1];
            float4 cv2 = crow[b * 4 + 2];
            float4 cv3 = crow[b * 4 + 3];
            const float* qb = qv + b * 16;
            float d0, d1, d2, d3;
            d0 = qb[ 0] - cv0.x; d1 = qb[ 1] - cv0.y; d2 = qb[ 2] - cv0.z; d3 = qb[ 3] - cv0.w;
            acc[0] = __builtin_fmaf(d0, d0, acc[0]);
            acc[1] = __builtin_fmaf(d1, d1, acc[1]);
            acc[2] = __builtin_fmaf(d2, d2, acc[2]);
            acc[3] = __builtin_fmaf(d3, d3, acc[3]);
            d0 = qb[ 4] - cv1.x; d1 = qb[ 5] - cv1.y; d2 = qb[ 6] - cv1.z; d3 = qb[ 7] - cv1.w;
            acc[4] = __builtin_fmaf(d0, d0, acc[4]);
            acc[5] = __builtin_fmaf(d1, d1, acc[5]);
            acc[6] = __builtin_fmaf(d2, d2, acc[6]);
            acc[7] = __builtin_fmaf(d3, d3, acc[7]);
            d0 = qb[ 8] - cv2.x; d1 = qb[ 9] - cv2.y; d2 = qb[10] - cv2.z; d3 = qb[11] - cv2.w;
            acc[0] = __builtin_fmaf(d0, d0, acc[0]);
            acc[1] = __builtin_fmaf(d1, d1, acc[1]);
            acc[2] = __builtin_fmaf(d2, d2, acc[2]);
            acc[3] = __builtin_fmaf(d3, d3, acc[3]);
            d0 = qb[12] - cv3.x; d1 = qb[13] - cv3.y; d2 = qb[14] - cv3.z; d3 = qb[15] - cv3.w;
            acc[4] = __builtin_fmaf(d0, d0, acc[4]);
            acc[5] = __builtin_fmaf(d1, d1, acc[5]);
            acc[6] = __builtin_fmaf(d2, d2, acc[6]);
            acc[7] = __builtin_fmaf(d3, d3, acc[7]);
        }

        float s = ((acc[0] + acc[1]) + (acc[2] + acc[3]))
                + ((acc[4] + acc[5]) + (acc[6] + acc[7]));
        float n = sqrtf(s);               // same norm-space compare as ref
        if (n < best) {                   // strict <, ascending code index
            best = n;
            bidx = code;
        }
    }

    wnorm[(size_t)chunk * NQ + q] = best;
    widx [(size_t)chunk * NQ + q] = bidx;
}

// Reduce the 32 chunk-partials per query (ascending -> first-occurrence
// tie-break), write k (as float) and gather z_q coalesced.
__global__ __launch_bounds__(256) void vq_finalize_kernel(
    const float* __restrict__ table,
    const float* __restrict__ wnorm,
    const int* __restrict__ widx,
    float* __restrict__ out)
{
    const int gid = blockIdx.x * 256 + threadIdx.x;   // 0 .. NQ*64
    const int q = gid >> 6;
    const int d = gid & 63;

    float best = INFINITY;
    int   bidx = 0;
#pragma unroll
    for (int p = 0; p < NCHUNK; ++p) {
        float n = wnorm[(size_t)p * NQ + q];          // wave-uniform broadcast
        int   i = widx [(size_t)p * NQ + q];
        if (n < best || (n == best && i < bidx)) { best = n; bidx = i; }
    }

    out[NQ + (size_t)q * VDIM + d] = table[(size_t)bidx * VDIM + d];
    if (d == 0) out[q] = (float)bidx;
}

extern "C" void kernel_launch(void* const* d_in, const int* in_sizes, int n_in,
                              void* d_out, int out_size, void* d_ws, size_t ws_size,
                              hipStream_t stream) {
    const float* inp   = (const float*)d_in[0];   // [4,2048,64] fp32
    const float* table = (const float*)d_in[1];   // [512,64]    fp32
    float* out = (float*)d_out;

    float* wnorm = (float*)d_ws;                        // NCHUNK*NQ floats (1 MB)
    int*   widx  = (int*)(wnorm + (size_t)NCHUNK * NQ); // NCHUNK*NQ ints   (1 MB)

    // 32 chunks x 32 query-quads = 1024 blocks x 256 thr = 4096 waves
    vq_dist_kernel<<<dim3(NCHUNK * 32), dim3(256), 0, stream>>>(inp, table, wnorm, widx);
    vq_finalize_kernel<<<dim3((NQ * VDIM) / 256), dim3(256), 0, stream>>>(table, wnorm, widx, out);
}